// Round 2
// baseline (115.371 us; speedup 1.0000x reference)
//
#include <hip/hip_runtime.h>
#include <math.h>

// RoPE, interleaved layout: x shape (4, 16, 4096, 64) fp32.
// out[..., 2i]   = cos(a_i)*x[2i] - sin(a_i)*x[2i+1]
// out[..., 2i+1] = sin(a_i)*x[2i] + cos(a_i)*x[2i+1]
// a_i = pos * 10000^(-i/32), pos = seq index (reference ignores token_positions).
//
// MEASURED ladder (session):
//   1 float4/thread, plain ld/st, hw v_sin/v_cos  -> 110.3 µs
//   1 float4/thread, libm sincosf                 -> 110.5 µs
//   2 float4/thread, plain                        -> 113.2 µs (fewer waves)
//   2 float4/thread, nontemporal stores           -> 119.3 µs (nt stores kill
//                                                   L2 write-smoothing)
// THIS ROUND: nontemporal LOADS only (read stream is touch-once; keep it out
// of L2 so the write stream owns L2 capacity), regular stores. Round-1 retry:
// __builtin_nontemporal_load needs a NATIVE vector type, not HIP_vector_type
// -> use clang ext_vector_type(4) float.
// Kernel slice ≈ 25 µs of 134 MB mixed r/w ≈ 5.4 TB/s vs 6.3 TB/s copy
// ceiling; the rest of dur_us is fixed harness poison/restore (~83 µs of
// fillBuffer dispatches).
// Trig: angle in revolutions (1/2π folded into inv_freq), fract reduction,
// hardware sin/cos. absmax 0.0313 vs threshold 0.115.

typedef float floatx4 __attribute__((ext_vector_type(4)));

__global__ __launch_bounds__(256) void
rope_kernel(const floatx4* __restrict__ x, floatx4* __restrict__ out, int n4) {
    int t = blockIdx.x * blockDim.x + threadIdx.x;
    if (t >= n4) return;

    // Nontemporal load: stream-once data, don't allocate in cache.
    floatx4 v = __builtin_nontemporal_load(&x[t]);

    unsigned e = (unsigned)t << 2;        // flat element index of v.x
    unsigned d = e & 63u;                 // offset within head dim (mult of 4)
    unsigned pos = (e >> 6) & 4095u;      // sequence position
    float fpos = (float)pos;

    float p0 = (float)(d >> 1);           // pair index for (v.x,v.y)

    // inv_freq in REVOLUTIONS: 10000^(-p/32) / (2*pi)
    const float kA = -0.41524101186092503f;  // -log2(10000)/32
    const float kB = -2.6514961294723187f;   // -log2(2*pi)
    const float kStep = 0.7498942093324559f; // 10000^(-1/32)
    float invf0 = exp2f(fmaf(p0, kA, kB));
    float invf1 = invf0 * kStep;

    float r0 = fpos * invf0; r0 -= floorf(r0);
    float r1 = fpos * invf1; r1 -= floorf(r1);

    float s0 = __builtin_amdgcn_sinf(r0), c0 = __builtin_amdgcn_cosf(r0);
    float s1 = __builtin_amdgcn_sinf(r1), c1 = __builtin_amdgcn_cosf(r1);

    floatx4 r;
    r.x = c0 * v.x - s0 * v.y;
    r.y = s0 * v.x + c0 * v.y;
    r.z = c1 * v.z - s1 * v.w;
    r.w = s1 * v.z + c1 * v.w;
    out[t] = r;   // regular store: keep L2 write-smoothing
}

extern "C" void kernel_launch(void* const* d_in, const int* in_sizes, int n_in,
                              void* d_out, int out_size, void* d_ws, size_t ws_size,
                              hipStream_t stream) {
    const floatx4* x = (const floatx4*)d_in[0];
    floatx4* out = (floatx4*)d_out;
    int n4 = out_size / 4;  // 16,777,216 / 4 = 4,194,304

    const int block = 256;
    const int grid = (n4 + block - 1) / block;  // 16384
    rope_kernel<<<grid, block, 0, stream>>>(x, out, n4);
}

// Round 3
// 110.308 us; speedup vs baseline: 1.0459x; 1.0459x over previous
//
#include <hip/hip_runtime.h>
#include <math.h>

// RoPE, interleaved layout: x shape (4, 16, 4096, 64) fp32.
// out[..., 2i]   = cos(a_i)*x[2i] - sin(a_i)*x[2i+1]
// out[..., 2i+1] = sin(a_i)*x[2i] + cos(a_i)*x[2i+1]
// a_i = pos * 10000^(-i/32), pos = seq index (reference ignores token_positions).
//
// MEASURED ladder (complete — all memory-path levers A/B'd on HW):
//   1 float4/thread, plain ld/st, hw v_sin/v_cos  -> 110.1-110.3 µs  (THIS)
//   1 float4/thread, libm sincosf                 -> 110.5 µs
//   2 float4/thread, plain                        -> 113.2 µs (fewer waves ->
//                                                   fewer concurrent streams)
//   1 float4/thread, nontemporal LOADS            -> 115.4 µs (input is
//       L2/L3-warm from harness restore; nt forfeits those hits)
//   2 float4/thread, nontemporal STORES           -> 119.3 µs (nt defeats L2
//                                                   write-smoothing)
// Roofline: 134.2 MB mixed r/w; kernel slice ~25 µs ≈ 5.4 TB/s vs 6.3 TB/s
// copy ceiling (float4-copy µbench). ~83 µs of dur_us is fixed harness
// poison/restore (2x 41.5 µs fillBuffer). Plain caching is optimal because
// the input is cache-warm; both nt hints measured as regressions.
// Trig: angle in revolutions (1/2π folded into inv_freq), fract reduction,
// hardware sin/cos. absmax 0.0313 vs threshold 0.115.

__global__ __launch_bounds__(256) void
rope_kernel(const float4* __restrict__ x, float4* __restrict__ out, int n4) {
    int t = blockIdx.x * blockDim.x + threadIdx.x;
    if (t >= n4) return;

    float4 v = x[t];

    unsigned e = (unsigned)t << 2;        // flat element index of v.x
    unsigned d = e & 63u;                 // offset within head dim (mult of 4)
    unsigned pos = (e >> 6) & 4095u;      // sequence position
    float fpos = (float)pos;

    float p0 = (float)(d >> 1);           // pair index for (v.x,v.y)

    // inv_freq in REVOLUTIONS: 10000^(-p/32) / (2*pi)
    const float kA = -0.41524101186092503f;  // -log2(10000)/32
    const float kB = -2.6514961294723187f;   // -log2(2*pi)
    const float kStep = 0.7498942093324559f; // 10000^(-1/32)
    float invf0 = exp2f(fmaf(p0, kA, kB));
    float invf1 = invf0 * kStep;

    float r0 = fpos * invf0; r0 -= floorf(r0);
    float r1 = fpos * invf1; r1 -= floorf(r1);

    float s0 = __builtin_amdgcn_sinf(r0), c0 = __builtin_amdgcn_cosf(r0);
    float s1 = __builtin_amdgcn_sinf(r1), c1 = __builtin_amdgcn_cosf(r1);

    float4 r;
    r.x = c0 * v.x - s0 * v.y;
    r.y = s0 * v.x + c0 * v.y;
    r.z = c1 * v.z - s1 * v.w;
    r.w = s1 * v.z + c1 * v.w;
    out[t] = r;
}

extern "C" void kernel_launch(void* const* d_in, const int* in_sizes, int n_in,
                              void* d_out, int out_size, void* d_ws, size_t ws_size,
                              hipStream_t stream) {
    const float4* x = (const float4*)d_in[0];
    float4* out = (float4*)d_out;
    int n4 = out_size / 4;  // 16,777,216 / 4 = 4,194,304

    const int block = 256;
    const int grid = (n4 + block - 1) / block;  // 16384
    rope_kernel<<<grid, block, 0, stream>>>(x, out, n4);
}